// Round 7
// baseline (75.667 us; speedup 1.0000x reference)
//
#include <hip/hip_runtime.h>

typedef __bf16 bf16x8 __attribute__((ext_vector_type(8)));
typedef float f32x4 __attribute__((ext_vector_type(4)));
typedef float f32x16 __attribute__((ext_vector_type(16)));

__device__ __forceinline__ unsigned short f2bf(float x) {
  union { float f; unsigned u; } a; a.f = x;
  unsigned r = a.u + 0x7FFFu + ((a.u >> 16) & 1u);
  return (unsigned short)(r >> 16);
}

__device__ __forceinline__ float exp2f_fast(float x) {
  return __builtin_amdgcn_exp2f(x);
}

__device__ __forceinline__ unsigned cvtpk_bf16(float lo, float hi) {
  unsigned r;
  asm("v_cvt_pk_bf16_f32 %0, %1, %2" : "=v"(r) : "v"(lo), "v"(hi));
  return r;
}

__device__ __forceinline__ void gl_lds16(const void* g, void* l) {
  __builtin_amdgcn_global_load_lds(
      (const __attribute__((address_space(1))) void*)g,
      (__attribute__((address_space(3))) void*)l, 16, 0, 0);
}

__device__ __forceinline__ int swap23(int x) {  // swap bits 2 and 3
  return (x & ~12) | ((x & 4) << 1) | ((x & 8) >> 1);
}

// ---------------------------------------------------------------------------
// Fused prep (unchanged from round 6).
//  [0,4096):    selection -> sm bitmasks
//  [4096,4352): K -> Kt fragment-tiled bf16: Kt[kv][s][j][lane] (16B slots)
//  [4352,4608): V -> Vt fragment-tiled bf16: Vt[kv][s][j'][lane]
// ---------------------------------------------------------------------------
__global__ __launch_bounds__(256) void prep_kernel(const float* __restrict__ k,
                                                   const float* __restrict__ v,
                                                   const float* __restrict__ p,
                                                   unsigned short* __restrict__ Kt,
                                                   unsigned short* __restrict__ Vt,
                                                   unsigned* __restrict__ sm) {
  const int bx = blockIdx.x;
  if (bx < 4096) {
    // --- selection, rank-based top-k (one wave per (kv, m))
    const int wid = bx * 4 + (threadIdx.x >> 6);
    const int lane = threadIdx.x & 63;
    const int kv = wid >> 11;
    const int m = wid & 2047;
    const int rb = m >> 6;
    const int s = lane & 31;
    const int c0 = 4 * s - 1;
    float best = -1.f;
    for (int g = 0; g < 2; ++g) {
      int h = kv * 4 + (lane >> 5) * 2 + g;
      const float* pr = p + ((size_t)h * 2048 + m) * 127;
      float acc = 0.f;
      if (c0 >= 0) acc = fmaf(pr[c0], 1.f, acc);
      acc = fmaf(pr[c0 + 1], 2.f, acc);
      acc = fmaf(pr[c0 + 2], 2.f, acc);
      acc = fmaf(pr[c0 + 3], 2.f, acc);
      if (c0 + 4 < 127) acc = fmaf(pr[c0 + 4], 1.f, acc);
      best = fmaxf(best, acc);
    }
    best = fmaxf(best, __shfl_xor(best, 32));
    const int rbm1 = rb > 0 ? rb - 1 : 0;
    if (s == 0 || s == rb || s == rbm1) best = 999999.0f;
    const int half = lane & 32;
    int cnt = 0;
#pragma unroll
    for (int o = 1; o <= 16; ++o) {
      int oo = half ? (o + 16) : o;
      int os = (s + oo) & 31;
      float ov = __shfl(best, half | os);
      bool gr = (ov > best) || (ov == best && os < s);
      cnt += (gr && oo < 32) ? 1 : 0;
    }
    int rank = cnt + __shfl_xor(cnt, 32);
    const int kmax = min(rb + 1, 16);
    unsigned long long bal = __ballot(rank < kmax);
    if (lane == 0) sm[(size_t)kv * 2048 + m] = (unsigned)(bal & 0xffffffffu);
  } else if (bx < 4352) {
    // --- K fragment tiler
    const int kvs = bx - 4096;                 // kv*32 + s
    const int kv = kvs >> 5, s = kvs & 31;
    const int lane = threadIdx.x & 63;
    const int jg = threadIdx.x >> 6;
    const int c = lane & 31, hb = lane >> 5;
    const int posl = swap23(c);
    unsigned short* dst = Kt + ((size_t)kvs << 13);
#pragma unroll
    for (int jj = 0; jj < 4; ++jj) {
      int j = jg * 4 + jj;
      int pos = s * 64 + ((j >> 3) << 5) + posl;
      int d0 = ((j & 7) << 4) + (hb << 3);
      const float* src = k + (((size_t)pos * 8 + kv) << 7) + d0;
      float4 a = *(const float4*)src;
      float4 b = *(const float4*)(src + 4);
      union { bf16x8 w; unsigned short u[8]; } t;
      t.u[0] = f2bf(a.x); t.u[1] = f2bf(a.y); t.u[2] = f2bf(a.z); t.u[3] = f2bf(a.w);
      t.u[4] = f2bf(b.x); t.u[5] = f2bf(b.y); t.u[6] = f2bf(b.z); t.u[7] = f2bf(b.w);
      *(bf16x8*)(dst + ((j * 64 + lane) << 3)) = t.w;
    }
  } else {
    // --- V fragment tiler (transposed gather)
    const int kvs = bx - 4352;
    const int kv = kvs >> 5, s = kvs & 31;
    const int lane = threadIdx.x & 63;
    const int jg = threadIdx.x >> 6;
    const int c = lane & 31, hb = lane >> 5;
    unsigned short* dst = Vt + ((size_t)kvs << 13);
#pragma unroll
    for (int jj = 0; jj < 4; ++jj) {
      int j = jg * 4 + jj;
      int db = j >> 2, kk = j & 3;
      int d = (db << 5) + c;
      int pos0 = s * 64 + (kk << 4) + (hb << 3);
      union { bf16x8 w; unsigned short u[8]; } t;
#pragma unroll
      for (int i = 0; i < 8; ++i)
        t.u[i] = f2bf(v[(((size_t)(pos0 + i) * 8 + kv) << 7) + d]);
      *(bf16x8*)(dst + ((j * 64 + lane) << 3)) = t.w;
    }
  }
}

// ---------------------------------------------------------------------------
// Attention round 7: WG = 32 rows x 4 heads (one kv), 4 waves x 32 cols.
// Per WG-stage, the 32KB K/V block is staged into LDS ONCE (global_load_lds,
// double-buffered, counted vmcnt) and all 4 waves fan out via conflict-free
// fragment-linear ds_read_b128 (base + j*1024 + lane*16). Cuts the saturated
// vL1D-return traffic 4x vs round 6. Compute path unchanged from round 6.
// grid 512 = 64 z x 8 kv; pair (wg, wg+256) sums to 33 stages on every CU.
// ---------------------------------------------------------------------------
__global__ __launch_bounds__(256, 2) void attn_kernel(
    const unsigned short* __restrict__ Kt,
    const unsigned short* __restrict__ Vt,
    const float* __restrict__ q,
    const unsigned* __restrict__ sm,
    float* __restrict__ out) {
  const int wg = blockIdx.x;
  const int kv = wg & 7;
  const int zi = wg >> 3;
  const int z = (zi < 32) ? (2 * zi + 1) : (126 - 2 * zi);  // pair-balanced
  const int m0 = z * 32;
  const int rb = z >> 1;
  const int tid = threadIdx.x;
  const int w = tid >> 6, lane = tid & 63;
  const int c = lane & 31, hb = lane >> 5;
  const int row = m0 + w * 8 + (c & 7);
  const int head = kv * 4 + (c >> 3);

  __shared__ unsigned short Kl[2][8192];  // 16KB per buf, fragment-linear
  __shared__ unsigned short Vl[2][8192];
  __shared__ unsigned Ush;

  // Q B-frags (scale * log2e folded in): lane holds col (row,head), k=16ks+8hb+i
  const float qs = 0.08838834764831845f * 1.4426950408889634f;
  bf16x8 qf[8];
  {
    const float* qp = q + ((size_t)row * 32 + head) * 128 + hb * 8;
#pragma unroll
    for (int ks = 0; ks < 8; ++ks) {
      float4 a = *(const float4*)(qp + ks * 16);
      float4 b = *(const float4*)(qp + ks * 16 + 4);
      union { bf16x8 v; unsigned w4[4]; } t;
      t.w4[0] = cvtpk_bf16(a.x * qs, a.y * qs);
      t.w4[1] = cvtpk_bf16(a.z * qs, a.w * qs);
      t.w4[2] = cvtpk_bf16(b.x * qs, b.y * qs);
      t.w4[3] = cvtpk_bf16(b.z * qs, b.w * qs);
      qf[ks] = t.v;
    }
  }
  const unsigned selr = sm[(size_t)kv * 2048 + row];
  unsigned aW = selr;
  aW |= __shfl_xor(aW, 1);
  aW |= __shfl_xor(aW, 2);
  aW |= __shfl_xor(aW, 4);           // union over the wave's 8 rows
  const unsigned cmask = (2u << rb) - 1u;
  aW &= cmask;
  if (tid == 0) Ush = 0;
  __syncthreads();
  if (lane == 0) atomicOr(&Ush, aW);
  __syncthreads();
  const unsigned U = Ush;            // WG union (already causal-capped)

  const unsigned short* KtKv = Kt + ((size_t)(kv * 32) << 13);
  const unsigned short* VtKv = Vt + ((size_t)(kv * 32) << 13);

  // Stage block si into buffer b: 8 gl_lds16 per wave (wave w owns frags 4w..4w+3
  // of both K and V). LDS dst = wave-uniform base; HW adds lane*16B.
  auto STAGE = [&](int b, int si) {
    const size_t so = (size_t)si << 13;
#pragma unroll
    for (int jj = 0; jj < 4; ++jj) {
      int j = w * 4 + jj;
      gl_lds16(KtKv + so + (j << 9) + (lane << 3), &Kl[b][j << 9]);
    }
#pragma unroll
    for (int jj = 0; jj < 4; ++jj) {
      int j = w * 4 + jj;
      gl_lds16(VtKv + so + (j << 9) + (lane << 3), &Vl[b][j << 9]);
    }
  };

  f32x16 oacc[4];
#pragma unroll
  for (int i = 0; i < 4; ++i)
#pragma unroll
    for (int e = 0; e < 16; ++e) oacc[i][e] = 0.f;
  float lrun = 0.f;

  int s = 0;  // bit 0 of U always set (block 0 forced for every row)
  int cur = 0;
  STAGE(0, 0);
  while (s >= 0) {
    int ns = -1;
    if (s < 31) {
      unsigned rest = U >> (s + 1);
      if (rest) ns = s + 1 + __builtin_ctz(rest);
    }
    if (ns >= 0) {
      STAGE(cur ^ 1, ns);
      asm volatile("s_waitcnt vmcnt(8)" ::: "memory");  // current buf landed
    } else {
      asm volatile("s_waitcnt vmcnt(0)" ::: "memory");
    }
    __builtin_amdgcn_s_barrier();
    asm volatile("" ::: "memory");
    if ((aW >> s) & 1u) {
      const unsigned short* KL = &Kl[cur][0];
      const unsigned short* VL = &Vl[cur][0];
      // --- K fragments: 16 conflict-free ds_read_b128
      bf16x8 kf[16];
#pragma unroll
      for (int j = 0; j < 16; ++j)
        kf[j] = *(const bf16x8*)&KL[(j << 9) + (lane << 3)];
      // --- QK^T (swapped: A=K, B=Q); acc pos-ascending per lane via swap23 tiling
      f32x16 a0 = {}, a1 = {};
#pragma unroll
      for (int ks = 0; ks < 8; ++ks)
        a0 = __builtin_amdgcn_mfma_f32_32x32x16_bf16(kf[ks], qf[ks], a0, 0, 0, 0);
#pragma unroll
      for (int ks = 0; ks < 8; ++ks)
        a1 = __builtin_amdgcn_mfma_f32_32x32x16_bf16(kf[8 + ks], qf[ks], a1, 0, 0, 0);
      // --- V fragments issued now; latency hides under softmax VALU
      bf16x8 vf[16];
#pragma unroll
      for (int j = 0; j < 16; ++j)
        vf[j] = *(const bf16x8*)&VL[(j << 9) + (lane << 3)];
      // --- mask + exp (fixed reference m=0)
      int lim = ((selr >> s) & 1u) ? ((s == rb) ? (row & 63) : 63) : -1;
      int limadj = lim - 8 * hb;
      float pv[32];
#pragma unroll
      for (int j = 0; j < 32; ++j) {
        int P0 = ((j >> 4) << 5) + (((j >> 3) & 1) << 4) + (j & 7);
        float x = (j < 16) ? a0[j & 15] : a1[j & 15];
        pv[j] = exp2f_fast((P0 <= limadj) ? x : -3.0e38f);
      }
      float s0[8];
#pragma unroll
      for (int j = 0; j < 8; ++j)
        s0[j] = (pv[4 * j] + pv[4 * j + 1]) + (pv[4 * j + 2] + pv[4 * j + 3]);
      float psum = ((s0[0] + s0[1]) + (s0[2] + s0[3])) + ((s0[4] + s0[5]) + (s0[6] + s0[7]));
      psum += __shfl_xor(psum, 32);
      lrun += psum;
      // --- P B-frags: pos-sequential pack, 16 cvt_pk
      bf16x8 pf[4];
#pragma unroll
      for (int kk = 0; kk < 4; ++kk) {
        union { bf16x8 v; unsigned w4[4]; } t;
        t.w4[0] = cvtpk_bf16(pv[8 * kk + 0], pv[8 * kk + 1]);
        t.w4[1] = cvtpk_bf16(pv[8 * kk + 2], pv[8 * kk + 3]);
        t.w4[2] = cvtpk_bf16(pv[8 * kk + 4], pv[8 * kk + 5]);
        t.w4[3] = cvtpk_bf16(pv[8 * kk + 6], pv[8 * kk + 7]);
        pf[kk] = t.v;
      }
      // --- PV (swapped: A=V^T, B=P^T)
#pragma unroll
      for (int jp = 0; jp < 16; ++jp)
        oacc[jp >> 2] = __builtin_amdgcn_mfma_f32_32x32x16_bf16(vf[jp], pf[jp & 3], oacc[jp >> 2], 0, 0, 0);
    }
    asm volatile("" ::: "memory");
    __builtin_amdgcn_s_barrier();
    cur ^= 1;
    s = ns;
  }
  // --- epilogue: O[row,head][d = db*32 + 8*rg + 4*hb + e]
  const float inv = 1.f / lrun;
  float* op = out + ((size_t)row * 32 + head) * 128;
#pragma unroll
  for (int db = 0; db < 4; ++db) {
#pragma unroll
    for (int rg = 0; rg < 4; ++rg) {
      float4 o4;
      o4.x = oacc[db][4 * rg + 0] * inv;
      o4.y = oacc[db][4 * rg + 1] * inv;
      o4.z = oacc[db][4 * rg + 2] * inv;
      o4.w = oacc[db][4 * rg + 3] * inv;
      *(float4*)&op[db * 32 + rg * 8 + hb * 4] = o4;
    }
  }
}

extern "C" void kernel_launch(void* const* d_in, const int* in_sizes, int n_in,
                              void* d_out, int out_size, void* d_ws, size_t ws_size,
                              hipStream_t stream) {
  const float* q = (const float*)d_in[0];
  const float* k = (const float*)d_in[1];
  const float* v = (const float*)d_in[2];
  const float* p = (const float*)d_in[3];
  float* out = (float*)d_out;
  unsigned short* Kt = (unsigned short*)d_ws;
  unsigned short* Vt = (unsigned short*)((char*)d_ws + (size_t)4 * 1024 * 1024);
  unsigned* sm = (unsigned*)((char*)d_ws + (size_t)8 * 1024 * 1024);

  prep_kernel<<<4608, 256, 0, stream>>>(k, v, p, Kt, Vt, sm);
  attn_kernel<<<512, 256, 0, stream>>>(Kt, Vt, q, sm, out);
}